// Round 7
// baseline (2366.450 us; speedup 1.0000x reference)
//
#include <hip/hip_runtime.h>
#include <cstdint>
#include <cstddef>

#define IN_CH 256

constexpr float BN_EPS = 1e-5f;

using u16x4 = __attribute__((ext_vector_type(4))) unsigned short;
using u16x8 = __attribute__((ext_vector_type(8))) unsigned short;
using bf16x8 = __attribute__((ext_vector_type(8))) short;
using f32x4 = __attribute__((ext_vector_type(4))) float;

__device__ __forceinline__ unsigned short f2bf_rne(float x) {
  unsigned u = __builtin_bit_cast(unsigned, x);
  unsigned r = u + 0x7FFFu + ((u >> 16) & 1u);
  return (unsigned short)(r >> 16);
}
__device__ __forceinline__ float bf2f(unsigned short h) {
  unsigned u = ((unsigned)h) << 16;
  return __builtin_bit_cast(float, u);
}

// ================= bucketed edge partition (no sort needed) =================
// pack = (dst & 255) << 17 | src   (src < 2^17); bucket = dst >> 8

#define NBK_MAX 400

__global__ __launch_bounds__(256) void bucket_hist(const int* __restrict__ dst,
                                                   int* __restrict__ bcnt, int E, int nbk) {
  __shared__ int c[NBK_MAX];
  for (int j = threadIdx.x; j < nbk; j += 256) c[j] = 0;
  __syncthreads();
  for (int i = blockIdx.x * 256 + threadIdx.x; i < E; i += gridDim.x * 256)
    atomicAdd(&c[dst[i] >> 8], 1);
  __syncthreads();
  for (int j = threadIdx.x; j < nbk; j += 256)
    if (c[j]) atomicAdd(&bcnt[j], c[j]);
}

__global__ void bucket_scan(const int* __restrict__ bcnt, int* __restrict__ boff,
                            int* __restrict__ gcur, int E, int nbk) {
  __shared__ int lds[512];
  int t = threadIdx.x;
  int v = (t < nbk) ? bcnt[t] : 0;
  lds[t] = v;
  __syncthreads();
  for (int s = 1; s < 512; s <<= 1) {
    int x = (t >= s) ? lds[t - s] : 0;
    __syncthreads();
    lds[t] += x;
    __syncthreads();
  }
  if (t < nbk) {
    boff[t] = lds[t] - v;
    gcur[t] = lds[t] - v;
  }
  if (t == 0) boff[nbk] = E;
}

__global__ __launch_bounds__(256) void partition(const int* __restrict__ src,
                                                 const int* __restrict__ dst,
                                                 int* __restrict__ gcur,
                                                 unsigned* __restrict__ part, int E, int nbk) {
  __shared__ int cnt[NBK_MAX];
  __shared__ int base[NBK_MAX];
  const int t = threadIdx.x;
  for (int j = t; j < nbk; j += 256) cnt[j] = 0;
  __syncthreads();
  const int e0 = blockIdx.x * 4096;
  unsigned mypk[16];
  int mybk[16];
#pragma unroll
  for (int u = 0; u < 16; ++u) {
    int e = e0 + u * 256 + t;
    if (e < E) {
      int d = dst[e];
      mypk[u] = (unsigned)src[e] | ((unsigned)(d & 255) << 17);
      mybk[u] = d >> 8;
      atomicAdd(&cnt[mybk[u]], 1);
    } else {
      mybk[u] = -1;
    }
  }
  __syncthreads();
  for (int j = t; j < nbk; j += 256) {
    int c = cnt[j];
    base[j] = c ? atomicAdd(&gcur[j], c) : 0;
    cnt[j] = 0;
  }
  __syncthreads();
#pragma unroll
  for (int u = 0; u < 16; ++u) {
    if (mybk[u] >= 0) {
      int r = atomicAdd(&cnt[mybk[u]], 1);
      part[base[mybk[u]] + r] = mypk[u];
    }
  }
}

// per-bucket degree histogram -> dinv
__global__ __launch_bounds__(256) void bucket_deg(const unsigned* __restrict__ part,
                                                  const int* __restrict__ boff,
                                                  float* __restrict__ dinv, int N) {
  __shared__ int cnt[256];
  const int b = blockIdx.x;
  const int t = threadIdx.x;
  cnt[t] = 0;
  __syncthreads();
  const int e0 = boff[b], ne = boff[b + 1] - e0;
  for (int i = t; i < ne; i += 256) atomicAdd(&cnt[(part[e0 + i] >> 17) & 255], 1);
  __syncthreads();
  int node = b * 256 + t;
  if (node < N) dinv[node] = rsqrtf((float)(cnt[t] + 1));  // +1 self loop
}

// ================= weight prep: transpose + hi/lo bf16 split =================

__global__ void wprep(const float* __restrict__ W, unsigned short* __restrict__ hi,
                      unsigned short* __restrict__ lo, int K, int N) {
  int i = blockIdx.x * 256 + threadIdx.x;
  if (i >= K * N) return;
  int k = i / N, n = i - k * N;
  float v = W[i];
  unsigned short h = f2bf_rne(v);
  hi[(size_t)n * K + k] = h;
  lo[(size_t)n * K + k] = f2bf_rne(v - bf2f(h));
}

// ================= MFMA GEMM =================
// Out (bf16) written COLUMN-SLICED: [8][M][BN/8], slice = c / (BN/8)

template <int K, int BN, bool BNRELU>
__global__ __launch_bounds__(256) void mfma_gemm(const float* __restrict__ A,
                                                 const unsigned short* __restrict__ Bt_hi,
                                                 const unsigned short* __restrict__ Bt_lo,
                                                 const float* __restrict__ ss,
                                                 const float* __restrict__ dinv,
                                                 unsigned short* __restrict__ Out, int M) {
  constexpr int BM = 128;
  constexpr int CS = BN / 8;  // 16 or 8
  __shared__ unsigned short Ah[BM * 32];
  __shared__ unsigned short Al[BM * 32];
  __shared__ unsigned short Bh[BN * 32];
  __shared__ unsigned short Bl[BN * 32];

  const int tid = threadIdx.x;
  const int wave = tid >> 6;
  const int lane = tid & 63;
  const int lg = lane >> 4;
  const int lr = lane & 15;
  const int row0 = blockIdx.x * BM;

  f32x4 acc[2][BN / 16];
#pragma unroll
  for (int f = 0; f < 2; ++f)
#pragma unroll
    for (int j = 0; j < BN / 16; ++j) acc[f][j] = (f32x4){0.f, 0.f, 0.f, 0.f};

  for (int k0 = 0; k0 < K; k0 += 32) {
    __syncthreads();
#pragma unroll
    for (int it = 0; it < 4; ++it) {
      int m = it * 32 + (tid >> 3);
      int c2 = tid & 7;
      float4 v = {0.f, 0.f, 0.f, 0.f};
      if (row0 + m < M) v = *(const float4*)&A[(size_t)(row0 + m) * K + k0 + c2 * 4];
      if constexpr (BNRELU) {
        int kk = k0 + c2 * 4;
        float4 sc = *(const float4*)&ss[kk];
        float4 sh = *(const float4*)&ss[K + kk];
        v.x = fmaxf(0.f, fmaf(v.x, sc.x, sh.x));
        v.y = fmaxf(0.f, fmaf(v.y, sc.y, sh.y));
        v.z = fmaxf(0.f, fmaf(v.z, sc.z, sh.z));
        v.w = fmaxf(0.f, fmaf(v.w, sc.w, sh.w));
      }
      float vv[4] = {v.x, v.y, v.z, v.w};
      u16x4 h4, l4;
#pragma unroll
      for (int i = 0; i < 4; ++i) {
        unsigned short h = f2bf_rne(vv[i]);
        h4[i] = h;
        l4[i] = f2bf_rne(vv[i] - bf2f(h));
      }
      int pr = (m >> 1) & 3;
      int base = m * 32 + (((c2 >> 1) ^ pr) * 8) + (c2 & 1) * 4;
      *(u16x4*)&Ah[base] = h4;
      *(u16x4*)&Al[base] = l4;
    }
#pragma unroll
    for (int it = 0; it < BN / 64; ++it) {
      int n = it * 64 + (tid >> 2);
      int c = tid & 3;
      int pr = (n >> 1) & 3;
      int base = n * 32 + ((c ^ pr) * 8);
      *(u16x8*)&Bh[base] = *(const u16x8*)&Bt_hi[(size_t)n * K + k0 + c * 8];
      *(u16x8*)&Bl[base] = *(const u16x8*)&Bt_lo[(size_t)n * K + k0 + c * 8];
    }
    __syncthreads();

    bf16x8 afh[2], afl[2];
#pragma unroll
    for (int f = 0; f < 2; ++f) {
      int m = wave * 32 + f * 16 + lr;
      int pr = (m >> 1) & 3;
      int base = m * 32 + ((lg ^ pr) * 8);
      afh[f] = *(const bf16x8*)&Ah[base];
      afl[f] = *(const bf16x8*)&Al[base];
    }
#pragma unroll
    for (int j = 0; j < BN / 16; ++j) {
      int n = j * 16 + lr;
      int pr = (n >> 1) & 3;
      int base = n * 32 + ((lg ^ pr) * 8);
      bf16x8 bh = *(const bf16x8*)&Bh[base];
      bf16x8 bl = *(const bf16x8*)&Bl[base];
#pragma unroll
      for (int f = 0; f < 2; ++f) {
        acc[f][j] = __builtin_amdgcn_mfma_f32_16x16x32_bf16(afh[f], bh, acc[f][j], 0, 0, 0);
        acc[f][j] = __builtin_amdgcn_mfma_f32_16x16x32_bf16(afl[f], bh, acc[f][j], 0, 0, 0);
        acc[f][j] = __builtin_amdgcn_mfma_f32_16x16x32_bf16(afh[f], bl, acc[f][j], 0, 0, 0);
      }
    }
  }

  // epilogue: scale by dinv, store bf16 column-sliced [8][M][CS]
#pragma unroll
  for (int f = 0; f < 2; ++f) {
#pragma unroll
    for (int r4 = 0; r4 < 4; ++r4) {
      int r = row0 + wave * 32 + f * 16 + lg * 4 + r4;
      if (r >= M) continue;
      float dv = dinv[r];
#pragma unroll
      for (int j = 0; j < BN / 16; ++j) {
        int c = j * 16 + lr;
        int slice = c / CS;
        int wi = c % CS;
        Out[((size_t)slice * M + r) * CS + wi] = f2bf_rne(acc[f][j][r4] * dv);
      }
    }
  }
}

// ================= edge-parallel bucket aggregation into LDS =================
// g column-sliced [8][N][CS] bf16. Block = (slice s, bucket b of 256 nodes).
// LDS acc[256][CS+pad] fp32, init with self row; stream bucket edges from
// `part` uniformly over all 256 threads (LPE lanes/edge, 4 batches in
// flight); ds_add_f32 accumulate; epilogue scales by dinv, writes out
// row-major, fuses BN partial stats.

template <int CS, bool STATS, bool BIAS>
__global__ __launch_bounds__(256) void agg_bucket(const unsigned* __restrict__ part,
                                                  const int* __restrict__ boff,
                                                  const unsigned short* __restrict__ g,
                                                  const float* __restrict__ dinv,
                                                  const float* __restrict__ bias,
                                                  float* __restrict__ out,
                                                  float* __restrict__ stat, int N) {
  constexpr int C = 8 * CS;
  constexpr int LPE = CS / 2;    // lanes per edge (8 or 4)
  constexpr int EPI = 256 / LPE; // edges per block-iteration (32 or 64)
  constexpr int PAD = CS + 1;    // padded fp32 stride (17 or 9)
  __shared__ float acc[256 * PAD];
  __shared__ float red[256][4];

  const int s = blockIdx.x;  // slice -> XCD (linear dispatch % 8)
  const int b = blockIdx.y;
  const int t = threadIdx.x;
  const int gi = t / LPE;
  const int cb = (t % LPE) * 2;  // channel pair within slice
  const unsigned short* gs = g + (size_t)s * N * CS;
  const int node0 = b * 256;
  const int e0 = boff[b];
  const int ne = boff[b + 1] - e0;

  // init acc with self-contribution (coalesced)
#pragma unroll
  for (int i = t; i < 256 * LPE; i += 256) {
    int nl = i / LPE, cc = (i % LPE) * 2;
    unsigned u = 0;
    if (node0 + nl < N) u = *(const unsigned*)&gs[(size_t)(node0 + nl) * CS + cc];
    acc[nl * PAD + cc] = __builtin_bit_cast(float, u << 16);
    acc[nl * PAD + cc + 1] = __builtin_bit_cast(float, u & 0xffff0000u);
  }
  __syncthreads();

  // edge loop: 4 independent batches per iteration
  for (int eb = 0; eb < ne; eb += 4 * EPI) {
    unsigned p[4], u[4];
#pragma unroll
    for (int q = 0; q < 4; ++q) {
      int e = eb + q * EPI + gi;
      p[q] = (e < ne) ? part[e0 + e] : 0xFFFFFFFFu;
    }
#pragma unroll
    for (int q = 0; q < 4; ++q) {
      u[q] = 0u;
      if (p[q] != 0xFFFFFFFFu)
        u[q] = *(const unsigned*)&gs[(size_t)(p[q] & 0x1FFFF) * CS + cb];
    }
#pragma unroll
    for (int q = 0; q < 4; ++q) {
      if (p[q] != 0xFFFFFFFFu) {
        int dl = (p[q] >> 17) & 255;
        atomicAdd(&acc[dl * PAD + cb], __builtin_bit_cast(float, u[q] << 16));
        atomicAdd(&acc[dl * PAD + cb + 1], __builtin_bit_cast(float, u[q] & 0xffff0000u));
      }
    }
  }
  __syncthreads();

  // epilogue: scale, bias, write out, BN partial stats
  float sx = 0.f, sy = 0.f, qx = 0.f, qy = 0.f;
#pragma unroll
  for (int i = t; i < 256 * LPE; i += 256) {
    int nl = i / LPE;
    int node = node0 + nl;
    if (node < N) {
      float dv = dinv[node];
      float ox = acc[nl * PAD + cb] * dv;
      float oy = acc[nl * PAD + cb + 1] * dv;
      if constexpr (BIAS) {
        ox += bias[s * CS + cb];
        oy += bias[s * CS + cb + 1];
      }
      *(float2*)&out[(size_t)node * C + s * CS + cb] = (float2){ox, oy};
      if constexpr (STATS) {
        sx += ox;
        sy += oy;
        qx += ox * ox;
        qy += oy * oy;
      }
    }
  }

  if constexpr (STATS) {
    red[t][0] = sx;
    red[t][1] = sy;
    red[t][2] = qx;
    red[t][3] = qy;
    __syncthreads();
    if (t < LPE) {
      float a0 = 0.f, a1 = 0.f, a2 = 0.f, a3 = 0.f;
      for (int k = t; k < 256; k += LPE) {
        a0 += red[k][0];
        a1 += red[k][1];
        a2 += red[k][2];
        a3 += red[k][3];
      }
      atomicAdd(&stat[s * CS + t * 2], a0);
      atomicAdd(&stat[s * CS + t * 2 + 1], a1);
      atomicAdd(&stat[C + s * CS + t * 2], a2);
      atomicAdd(&stat[C + s * CS + t * 2 + 1], a3);
    }
  }
}

// ================= BN finalize =================

template <int C>
__global__ void bn_finalize(const float* __restrict__ stat, const float* __restrict__ gamma,
                            const float* __restrict__ beta, float* __restrict__ ss, int N) {
  int c = threadIdx.x;
  if (c >= C) return;
  float mu = stat[c] / (float)N;
  float var = stat[C + c] / (float)N - mu * mu;
  float rs = rsqrtf(var + BN_EPS);
  float sc = gamma[c] * rs;
  ss[c] = sc;
  ss[C + c] = beta[c] - mu * sc;
}

// ================= launch =================

extern "C" void kernel_launch(void* const* d_in, const int* in_sizes, int n_in, void* d_out,
                              int out_size, void* d_ws, size_t ws_size, hipStream_t stream) {
  const float* x = (const float*)d_in[0];
  const int* ei = (const int*)d_in[1];
  const float* W1 = (const float*)d_in[2];
  const float* gamma1 = (const float*)d_in[4];
  const float* beta1 = (const float*)d_in[5];
  const float* W2 = (const float*)d_in[6];
  const float* gamma2 = (const float*)d_in[8];
  const float* beta2 = (const float*)d_in[9];
  const float* W3 = (const float*)d_in[10];
  const float* b3 = (const float*)d_in[11];
  float* out = (float*)d_out;

  const int N = in_sizes[0] / IN_CH;  // 100000
  const int E = in_sizes[1] / 2;      // 1600000
  const int* e_src = ei;
  const int* e_dst = ei + E;
  const int nbk = (N + 255) >> 8;  // 391

  char* ws = (char*)d_ws;
  size_t off = 0;
  auto alloc = [&](size_t bytes) {
    size_t r = off;
    off += (bytes + 1023) & ~(size_t)1023;
    return r;
  };
  int* bcnt = (int*)(ws + alloc(NBK_MAX * 4));
  int* boff = (int*)(ws + alloc((NBK_MAX + 1) * 4));
  int* gcur = (int*)(ws + alloc(NBK_MAX * 4));
  unsigned* part = (unsigned*)(ws + alloc((size_t)E * 4));
  float* dinv = (float*)(ws + alloc((size_t)N * 4));
  unsigned short* Wt1h = (unsigned short*)(ws + alloc(256 * 128 * 2));
  unsigned short* Wt1l = (unsigned short*)(ws + alloc(256 * 128 * 2));
  unsigned short* Wt2h = (unsigned short*)(ws + alloc(128 * 64 * 2));
  unsigned short* Wt2l = (unsigned short*)(ws + alloc(128 * 64 * 2));
  unsigned short* Wt3h = (unsigned short*)(ws + alloc(64 * 64 * 2));
  unsigned short* Wt3l = (unsigned short*)(ws + alloc(64 * 64 * 2));
  float* stat1 = (float*)(ws + alloc(256 * 4));
  float* stat2 = (float*)(ws + alloc(128 * 4));
  float* ss1 = (float*)(ws + alloc(256 * 4));
  float* ss2 = (float*)(ws + alloc(128 * 4));
  unsigned short* g = (unsigned short*)(ws + alloc((size_t)N * 128 * 2));
  float* h = (float*)(ws + alloc((size_t)N * 128 * 4));

  hipMemsetAsync(bcnt, 0, NBK_MAX * 4, stream);
  hipMemsetAsync(stat1, 0, 256 * 4, stream);
  hipMemsetAsync(stat2, 0, 128 * 4, stream);

  bucket_hist<<<2048, 256, 0, stream>>>(e_dst, bcnt, E, nbk);
  bucket_scan<<<1, 512, 0, stream>>>(bcnt, boff, gcur, E, nbk);
  partition<<<(E + 4095) / 4096, 256, 0, stream>>>(e_src, e_dst, gcur, part, E, nbk);
  bucket_deg<<<nbk, 256, 0, stream>>>(part, boff, dinv, N);

  wprep<<<(256 * 128 + 255) / 256, 256, 0, stream>>>(W1, Wt1h, Wt1l, 256, 128);
  wprep<<<(128 * 64 + 255) / 256, 256, 0, stream>>>(W2, Wt2h, Wt2l, 128, 64);
  wprep<<<(64 * 64 + 255) / 256, 256, 0, stream>>>(W3, Wt3h, Wt3l, 64, 64);

  const int gM = (N + 127) / 128;  // 782
  const dim3 gAgg(8, nbk);         // slice x bucket

  // ---- layer 1: 256 -> 128 ----
  mfma_gemm<256, 128, false><<<gM, 256, 0, stream>>>(x, Wt1h, Wt1l, nullptr, dinv, g, N);
  agg_bucket<16, true, false><<<gAgg, 256, 0, stream>>>(part, boff, g, dinv, nullptr, h, stat1, N);
  bn_finalize<128><<<1, 128, 0, stream>>>(stat1, gamma1, beta1, ss1, N);

  // ---- layer 2: 128 -> 64 (BN+ReLU fused into A staging) ----
  mfma_gemm<128, 64, true><<<gM, 256, 0, stream>>>(h, Wt2h, Wt2l, ss1, dinv, g, N);
  agg_bucket<8, true, false><<<gAgg, 256, 0, stream>>>(part, boff, g, dinv, nullptr, h, stat2, N);
  bn_finalize<64><<<1, 64, 0, stream>>>(stat2, gamma2, beta2, ss2, N);

  // ---- layer 3: 64 -> 64 ----
  mfma_gemm<64, 64, true><<<gM, 256, 0, stream>>>(h, Wt3h, Wt3l, ss2, dinv, g, N);
  agg_bucket<8, false, true><<<gAgg, 256, 0, stream>>>(part, boff, g, dinv, b3, out, nullptr, N);
}

// Round 8
// 2361.002 us; speedup vs baseline: 1.0023x; 1.0023x over previous
//
#include <hip/hip_runtime.h>
#include <cstdint>
#include <cstddef>

#define IN_CH 256

constexpr float BN_EPS = 1e-5f;

using u16x4 = __attribute__((ext_vector_type(4))) unsigned short;
using u16x8 = __attribute__((ext_vector_type(8))) unsigned short;
using bf16x8 = __attribute__((ext_vector_type(8))) short;
using f32x4 = __attribute__((ext_vector_type(4))) float;

__device__ __forceinline__ unsigned short f2bf_rne(float x) {
  unsigned u = __builtin_bit_cast(unsigned, x);
  unsigned r = u + 0x7FFFu + ((u >> 16) & 1u);
  return (unsigned short)(r >> 16);
}
__device__ __forceinline__ float bf2f(unsigned short h) {
  unsigned u = ((unsigned)h) << 16;
  return __builtin_bit_cast(float, u);
}

// hardware fp32 add (ds_add_f32 / global_atomic_add_f32), no CAS loop
__device__ __forceinline__ void fadd_hw(float* p, float v) { unsafeAtomicAdd(p, v); }

// ================= bucketed edge partition (no sort needed) =================
// pack = (dst & 255) << 17 | src   (src < 2^17); bucket = dst >> 8

#define NBK_MAX 400

__global__ __launch_bounds__(256) void bucket_hist(const int* __restrict__ dst,
                                                   int* __restrict__ bcnt, int E, int nbk) {
  __shared__ int c[NBK_MAX];
  for (int j = threadIdx.x; j < nbk; j += 256) c[j] = 0;
  __syncthreads();
  for (int i = blockIdx.x * 256 + threadIdx.x; i < E; i += gridDim.x * 256)
    atomicAdd(&c[dst[i] >> 8], 1);
  __syncthreads();
  for (int j = threadIdx.x; j < nbk; j += 256)
    if (c[j]) atomicAdd(&bcnt[j], c[j]);
}

__global__ void bucket_scan(const int* __restrict__ bcnt, int* __restrict__ boff,
                            int* __restrict__ gcur, int E, int nbk) {
  __shared__ int lds[512];
  int t = threadIdx.x;
  int v = (t < nbk) ? bcnt[t] : 0;
  lds[t] = v;
  __syncthreads();
  for (int s = 1; s < 512; s <<= 1) {
    int x = (t >= s) ? lds[t - s] : 0;
    __syncthreads();
    lds[t] += x;
    __syncthreads();
  }
  if (t < nbk) {
    boff[t] = lds[t] - v;
    gcur[t] = lds[t] - v;
  }
  if (t == 0) boff[nbk] = E;
}

__global__ __launch_bounds__(256) void partition(const int* __restrict__ src,
                                                 const int* __restrict__ dst,
                                                 int* __restrict__ gcur,
                                                 unsigned* __restrict__ part, int E, int nbk) {
  __shared__ int cnt[NBK_MAX];
  __shared__ int base[NBK_MAX];
  const int t = threadIdx.x;
  for (int j = t; j < nbk; j += 256) cnt[j] = 0;
  __syncthreads();
  const int e0 = blockIdx.x * 4096;
  unsigned mypk[16];
  int mybk[16];
#pragma unroll
  for (int u = 0; u < 16; ++u) {
    int e = e0 + u * 256 + t;
    if (e < E) {
      int d = dst[e];
      mypk[u] = (unsigned)src[e] | ((unsigned)(d & 255) << 17);
      mybk[u] = d >> 8;
      atomicAdd(&cnt[mybk[u]], 1);
    } else {
      mybk[u] = -1;
    }
  }
  __syncthreads();
  for (int j = t; j < nbk; j += 256) {
    int c = cnt[j];
    base[j] = c ? atomicAdd(&gcur[j], c) : 0;
    cnt[j] = 0;
  }
  __syncthreads();
#pragma unroll
  for (int u = 0; u < 16; ++u) {
    if (mybk[u] >= 0) {
      int r = atomicAdd(&cnt[mybk[u]], 1);
      part[base[mybk[u]] + r] = mypk[u];
    }
  }
}

// per-bucket degree histogram -> dinv
__global__ __launch_bounds__(256) void bucket_deg(const unsigned* __restrict__ part,
                                                  const int* __restrict__ boff,
                                                  float* __restrict__ dinv, int N) {
  __shared__ int cnt[256];
  const int b = blockIdx.x;
  const int t = threadIdx.x;
  cnt[t] = 0;
  __syncthreads();
  const int e0 = boff[b], ne = boff[b + 1] - e0;
  for (int i = t; i < ne; i += 256) atomicAdd(&cnt[(part[e0 + i] >> 17) & 255], 1);
  __syncthreads();
  int node = b * 256 + t;
  if (node < N) dinv[node] = rsqrtf((float)(cnt[t] + 1));  // +1 self loop
}

// ================= weight prep: transpose + hi/lo bf16 split =================

__global__ void wprep(const float* __restrict__ W, unsigned short* __restrict__ hi,
                      unsigned short* __restrict__ lo, int K, int N) {
  int i = blockIdx.x * 256 + threadIdx.x;
  if (i >= K * N) return;
  int k = i / N, n = i - k * N;
  float v = W[i];
  unsigned short h = f2bf_rne(v);
  hi[(size_t)n * K + k] = h;
  lo[(size_t)n * K + k] = f2bf_rne(v - bf2f(h));
}

// ================= MFMA GEMM =================
// Out (bf16) written COLUMN-SLICED: [8][M][BN/8], slice = c / (BN/8)

template <int K, int BN, bool BNRELU>
__global__ __launch_bounds__(256) void mfma_gemm(const float* __restrict__ A,
                                                 const unsigned short* __restrict__ Bt_hi,
                                                 const unsigned short* __restrict__ Bt_lo,
                                                 const float* __restrict__ ss,
                                                 const float* __restrict__ dinv,
                                                 unsigned short* __restrict__ Out, int M) {
  constexpr int BM = 128;
  constexpr int CS = BN / 8;  // 16 or 8
  __shared__ unsigned short Ah[BM * 32];
  __shared__ unsigned short Al[BM * 32];
  __shared__ unsigned short Bh[BN * 32];
  __shared__ unsigned short Bl[BN * 32];

  const int tid = threadIdx.x;
  const int wave = tid >> 6;
  const int lane = tid & 63;
  const int lg = lane >> 4;
  const int lr = lane & 15;
  const int row0 = blockIdx.x * BM;

  f32x4 acc[2][BN / 16];
#pragma unroll
  for (int f = 0; f < 2; ++f)
#pragma unroll
    for (int j = 0; j < BN / 16; ++j) acc[f][j] = (f32x4){0.f, 0.f, 0.f, 0.f};

  for (int k0 = 0; k0 < K; k0 += 32) {
    __syncthreads();
#pragma unroll
    for (int it = 0; it < 4; ++it) {
      int m = it * 32 + (tid >> 3);
      int c2 = tid & 7;
      float4 v = {0.f, 0.f, 0.f, 0.f};
      if (row0 + m < M) v = *(const float4*)&A[(size_t)(row0 + m) * K + k0 + c2 * 4];
      if constexpr (BNRELU) {
        int kk = k0 + c2 * 4;
        float4 sc = *(const float4*)&ss[kk];
        float4 sh = *(const float4*)&ss[K + kk];
        v.x = fmaxf(0.f, fmaf(v.x, sc.x, sh.x));
        v.y = fmaxf(0.f, fmaf(v.y, sc.y, sh.y));
        v.z = fmaxf(0.f, fmaf(v.z, sc.z, sh.z));
        v.w = fmaxf(0.f, fmaf(v.w, sc.w, sh.w));
      }
      float vv[4] = {v.x, v.y, v.z, v.w};
      u16x4 h4, l4;
#pragma unroll
      for (int i = 0; i < 4; ++i) {
        unsigned short h = f2bf_rne(vv[i]);
        h4[i] = h;
        l4[i] = f2bf_rne(vv[i] - bf2f(h));
      }
      int pr = (m >> 1) & 3;
      int base = m * 32 + (((c2 >> 1) ^ pr) * 8) + (c2 & 1) * 4;
      *(u16x4*)&Ah[base] = h4;
      *(u16x4*)&Al[base] = l4;
    }
#pragma unroll
    for (int it = 0; it < BN / 64; ++it) {
      int n = it * 64 + (tid >> 2);
      int c = tid & 3;
      int pr = (n >> 1) & 3;
      int base = n * 32 + ((c ^ pr) * 8);
      *(u16x8*)&Bh[base] = *(const u16x8*)&Bt_hi[(size_t)n * K + k0 + c * 8];
      *(u16x8*)&Bl[base] = *(const u16x8*)&Bt_lo[(size_t)n * K + k0 + c * 8];
    }
    __syncthreads();

    bf16x8 afh[2], afl[2];
#pragma unroll
    for (int f = 0; f < 2; ++f) {
      int m = wave * 32 + f * 16 + lr;
      int pr = (m >> 1) & 3;
      int base = m * 32 + ((lg ^ pr) * 8);
      afh[f] = *(const bf16x8*)&Ah[base];
      afl[f] = *(const bf16x8*)&Al[base];
    }
#pragma unroll
    for (int j = 0; j < BN / 16; ++j) {
      int n = j * 16 + lr;
      int pr = (n >> 1) & 3;
      int base = n * 32 + ((lg ^ pr) * 8);
      bf16x8 bh = *(const bf16x8*)&Bh[base];
      bf16x8 bl = *(const bf16x8*)&Bl[base];
#pragma unroll
      for (int f = 0; f < 2; ++f) {
        acc[f][j] = __builtin_amdgcn_mfma_f32_16x16x32_bf16(afh[f], bh, acc[f][j], 0, 0, 0);
        acc[f][j] = __builtin_amdgcn_mfma_f32_16x16x32_bf16(afl[f], bh, acc[f][j], 0, 0, 0);
        acc[f][j] = __builtin_amdgcn_mfma_f32_16x16x32_bf16(afh[f], bl, acc[f][j], 0, 0, 0);
      }
    }
  }

  // epilogue: scale by dinv, store bf16 column-sliced [8][M][CS]
#pragma unroll
  for (int f = 0; f < 2; ++f) {
#pragma unroll
    for (int r4 = 0; r4 < 4; ++r4) {
      int r = row0 + wave * 32 + f * 16 + lg * 4 + r4;
      if (r >= M) continue;
      float dv = dinv[r];
#pragma unroll
      for (int j = 0; j < BN / 16; ++j) {
        int c = j * 16 + lr;
        int slice = c / CS;
        int wi = c % CS;
        Out[((size_t)slice * M + r) * CS + wi] = f2bf_rne(acc[f][j][r4] * dv);
      }
    }
  }
}

// ================= edge-parallel bucket aggregation into LDS =================
// g column-sliced [8][N][CS] bf16. Block = (slice s, bucket b of 256 nodes).
// LDS acc[256][CS+pad] fp32, init with self row; stream bucket edges from
// `part` uniformly over all 256 threads (LPE lanes/edge, 4 batches in
// flight); ds_add_f32 (fire-and-forget HW atomic) accumulate; epilogue
// scales by dinv, writes out row-major, fuses BN partial stats.

template <int CS, bool STATS, bool BIAS>
__global__ __launch_bounds__(256) void agg_bucket(const unsigned* __restrict__ part,
                                                  const int* __restrict__ boff,
                                                  const unsigned short* __restrict__ g,
                                                  const float* __restrict__ dinv,
                                                  const float* __restrict__ bias,
                                                  float* __restrict__ out,
                                                  float* __restrict__ stat, int N) {
  constexpr int C = 8 * CS;
  constexpr int LPE = CS / 2;     // lanes per edge (8 or 4)
  constexpr int EPI = 256 / LPE;  // edges per block-iteration (32 or 64)
  constexpr int PAD = CS + 1;     // padded fp32 stride (17 or 9)
  __shared__ float acc[256 * PAD];
  __shared__ float red[256][4];

  const int s = blockIdx.x;  // slice -> XCD (linear dispatch % 8)
  const int b = blockIdx.y;
  const int t = threadIdx.x;
  const int gi = t / LPE;
  const int cb = (t % LPE) * 2;  // channel pair within slice
  const unsigned short* gs = g + (size_t)s * N * CS;
  const int node0 = b * 256;
  const int e0 = boff[b];
  const int ne = boff[b + 1] - e0;

  // init acc with self-contribution (coalesced)
#pragma unroll
  for (int i = t; i < 256 * LPE; i += 256) {
    int nl = i / LPE, cc = (i % LPE) * 2;
    unsigned u = 0;
    if (node0 + nl < N) u = *(const unsigned*)&gs[(size_t)(node0 + nl) * CS + cc];
    acc[nl * PAD + cc] = __builtin_bit_cast(float, u << 16);
    acc[nl * PAD + cc + 1] = __builtin_bit_cast(float, u & 0xffff0000u);
  }
  __syncthreads();

  // edge loop: 4 independent batches per iteration, HW ds_add accumulate
  for (int eb = 0; eb < ne; eb += 4 * EPI) {
    unsigned p[4], u[4];
#pragma unroll
    for (int q = 0; q < 4; ++q) {
      int e = eb + q * EPI + gi;
      p[q] = (e < ne) ? part[e0 + e] : 0xFFFFFFFFu;
    }
#pragma unroll
    for (int q = 0; q < 4; ++q) {
      u[q] = 0u;
      if (p[q] != 0xFFFFFFFFu)
        u[q] = *(const unsigned*)&gs[(size_t)(p[q] & 0x1FFFF) * CS + cb];
    }
#pragma unroll
    for (int q = 0; q < 4; ++q) {
      if (p[q] != 0xFFFFFFFFu) {
        int dl = (p[q] >> 17) & 255;
        fadd_hw(&acc[dl * PAD + cb], __builtin_bit_cast(float, u[q] << 16));
        fadd_hw(&acc[dl * PAD + cb + 1], __builtin_bit_cast(float, u[q] & 0xffff0000u));
      }
    }
  }
  __syncthreads();

  // epilogue: scale, bias, write out, BN partial stats
  float sx = 0.f, sy = 0.f, qx = 0.f, qy = 0.f;
#pragma unroll
  for (int i = t; i < 256 * LPE; i += 256) {
    int nl = i / LPE;
    int node = node0 + nl;
    if (node < N) {
      float dv = dinv[node];
      float ox = acc[nl * PAD + cb] * dv;
      float oy = acc[nl * PAD + cb + 1] * dv;
      if constexpr (BIAS) {
        ox += bias[s * CS + cb];
        oy += bias[s * CS + cb + 1];
      }
      *(float2*)&out[(size_t)node * C + s * CS + cb] = (float2){ox, oy};
      if constexpr (STATS) {
        sx += ox;
        sy += oy;
        qx += ox * ox;
        qy += oy * oy;
      }
    }
  }

  if constexpr (STATS) {
    red[t][0] = sx;
    red[t][1] = sy;
    red[t][2] = qx;
    red[t][3] = qy;
    __syncthreads();
    if (t < LPE) {
      float a0 = 0.f, a1 = 0.f, a2 = 0.f, a3 = 0.f;
      for (int k = t; k < 256; k += LPE) {
        a0 += red[k][0];
        a1 += red[k][1];
        a2 += red[k][2];
        a3 += red[k][3];
      }
      fadd_hw(&stat[s * CS + t * 2], a0);
      fadd_hw(&stat[s * CS + t * 2 + 1], a1);
      fadd_hw(&stat[C + s * CS + t * 2], a2);
      fadd_hw(&stat[C + s * CS + t * 2 + 1], a3);
    }
  }
}

// ================= BN finalize =================

template <int C>
__global__ void bn_finalize(const float* __restrict__ stat, const float* __restrict__ gamma,
                            const float* __restrict__ beta, float* __restrict__ ss, int N) {
  int c = threadIdx.x;
  if (c >= C) return;
  float mu = stat[c] / (float)N;
  float var = stat[C + c] / (float)N - mu * mu;
  float rs = rsqrtf(var + BN_EPS);
  float sc = gamma[c] * rs;
  ss[c] = sc;
  ss[C + c] = beta[c] - mu * sc;
}

// ================= launch =================

extern "C" void kernel_launch(void* const* d_in, const int* in_sizes, int n_in, void* d_out,
                              int out_size, void* d_ws, size_t ws_size, hipStream_t stream) {
  const float* x = (const float*)d_in[0];
  const int* ei = (const int*)d_in[1];
  const float* W1 = (const float*)d_in[2];
  const float* gamma1 = (const float*)d_in[4];
  const float* beta1 = (const float*)d_in[5];
  const float* W2 = (const float*)d_in[6];
  const float* gamma2 = (const float*)d_in[8];
  const float* beta2 = (const float*)d_in[9];
  const float* W3 = (const float*)d_in[10];
  const float* b3 = (const float*)d_in[11];
  float* out = (float*)d_out;

  const int N = in_sizes[0] / IN_CH;  // 100000
  const int E = in_sizes[1] / 2;      // 1600000
  const int* e_src = ei;
  const int* e_dst = ei + E;
  const int nbk = (N + 255) >> 8;  // 391

  char* ws = (char*)d_ws;
  size_t off = 0;
  auto alloc = [&](size_t bytes) {
    size_t r = off;
    off += (bytes + 1023) & ~(size_t)1023;
    return r;
  };
  int* bcnt = (int*)(ws + alloc(NBK_MAX * 4));
  int* boff = (int*)(ws + alloc((NBK_MAX + 1) * 4));
  int* gcur = (int*)(ws + alloc(NBK_MAX * 4));
  unsigned* part = (unsigned*)(ws + alloc((size_t)E * 4));
  float* dinv = (float*)(ws + alloc((size_t)N * 4));
  unsigned short* Wt1h = (unsigned short*)(ws + alloc(256 * 128 * 2));
  unsigned short* Wt1l = (unsigned short*)(ws + alloc(256 * 128 * 2));
  unsigned short* Wt2h = (unsigned short*)(ws + alloc(128 * 64 * 2));
  unsigned short* Wt2l = (unsigned short*)(ws + alloc(128 * 64 * 2));
  unsigned short* Wt3h = (unsigned short*)(ws + alloc(64 * 64 * 2));
  unsigned short* Wt3l = (unsigned short*)(ws + alloc(64 * 64 * 2));
  float* stat1 = (float*)(ws + alloc(256 * 4));
  float* stat2 = (float*)(ws + alloc(128 * 4));
  float* ss1 = (float*)(ws + alloc(256 * 4));
  float* ss2 = (float*)(ws + alloc(128 * 4));
  unsigned short* g = (unsigned short*)(ws + alloc((size_t)N * 128 * 2));
  float* h = (float*)(ws + alloc((size_t)N * 128 * 4));

  hipMemsetAsync(bcnt, 0, NBK_MAX * 4, stream);
  hipMemsetAsync(stat1, 0, 256 * 4, stream);
  hipMemsetAsync(stat2, 0, 128 * 4, stream);

  bucket_hist<<<2048, 256, 0, stream>>>(e_dst, bcnt, E, nbk);
  bucket_scan<<<1, 512, 0, stream>>>(bcnt, boff, gcur, E, nbk);
  partition<<<(E + 4095) / 4096, 256, 0, stream>>>(e_src, e_dst, gcur, part, E, nbk);
  bucket_deg<<<nbk, 256, 0, stream>>>(part, boff, dinv, N);

  wprep<<<(256 * 128 + 255) / 256, 256, 0, stream>>>(W1, Wt1h, Wt1l, 256, 128);
  wprep<<<(128 * 64 + 255) / 256, 256, 0, stream>>>(W2, Wt2h, Wt2l, 128, 64);
  wprep<<<(64 * 64 + 255) / 256, 256, 0, stream>>>(W3, Wt3h, Wt3l, 64, 64);

  const int gM = (N + 127) / 128;  // 782
  const dim3 gAgg(8, nbk);         // slice x bucket

  // ---- layer 1: 256 -> 128 ----
  mfma_gemm<256, 128, false><<<gM, 256, 0, stream>>>(x, Wt1h, Wt1l, nullptr, dinv, g, N);
  agg_bucket<16, true, false><<<gAgg, 256, 0, stream>>>(part, boff, g, dinv, nullptr, h, stat1, N);
  bn_finalize<128><<<1, 128, 0, stream>>>(stat1, gamma1, beta1, ss1, N);

  // ---- layer 2: 128 -> 64 (BN+ReLU fused into A staging) ----
  mfma_gemm<128, 64, true><<<gM, 256, 0, stream>>>(h, Wt2h, Wt2l, ss1, dinv, g, N);
  agg_bucket<8, true, false><<<gAgg, 256, 0, stream>>>(part, boff, g, dinv, nullptr, h, stat2, N);
  bn_finalize<64><<<1, 64, 0, stream>>>(stat2, gamma2, beta2, ss2, N);

  // ---- layer 3: 64 -> 64 ----
  mfma_gemm<64, 64, true><<<gM, 256, 0, stream>>>(h, Wt3h, Wt3l, ss2, dinv, g, N);
  agg_bucket<8, false, true><<<gAgg, 256, 0, stream>>>(part, boff, g, dinv, b3, out, nullptr, N);
}

// Round 9
// 371.870 us; speedup vs baseline: 6.3637x; 6.3490x over previous
//
#include <hip/hip_runtime.h>
#include <cstdint>
#include <cstddef>

#define IN_CH 256

constexpr float BN_EPS = 1e-5f;

using u16x4 = __attribute__((ext_vector_type(4))) unsigned short;
using u16x8 = __attribute__((ext_vector_type(8))) unsigned short;
using bf16x8 = __attribute__((ext_vector_type(8))) short;
using f32x4 = __attribute__((ext_vector_type(4))) float;

__device__ __forceinline__ unsigned short f2bf_rne(float x) {
  unsigned u = __builtin_bit_cast(unsigned, x);
  unsigned r = u + 0x7FFFu + ((u >> 16) & 1u);
  return (unsigned short)(r >> 16);
}
__device__ __forceinline__ float bf2f(unsigned short h) {
  unsigned u = ((unsigned)h) << 16;
  return __builtin_bit_cast(float, u);
}

// ================= CSR build: bucketed counting sort, coalesced IO =================
// pack = (dst & 255) << 17 | src   (src < 2^17)

#define NBK_MAX 400

__global__ __launch_bounds__(256) void bucket_hist(const int* __restrict__ dst,
                                                   int* __restrict__ bcnt, int E, int nbk) {
  __shared__ int c[NBK_MAX];
  for (int j = threadIdx.x; j < nbk; j += 256) c[j] = 0;
  __syncthreads();
  for (int i = blockIdx.x * 256 + threadIdx.x; i < E; i += gridDim.x * 256)
    atomicAdd(&c[dst[i] >> 8], 1);
  __syncthreads();
  for (int j = threadIdx.x; j < nbk; j += 256)
    if (c[j]) atomicAdd(&bcnt[j], c[j]);
}

__global__ void bucket_scan(const int* __restrict__ bcnt, int* __restrict__ boff,
                            int* __restrict__ gcur, int E, int nbk) {
  __shared__ int lds[512];
  int t = threadIdx.x;
  int v = (t < nbk) ? bcnt[t] : 0;
  lds[t] = v;
  __syncthreads();
  for (int s = 1; s < 512; s <<= 1) {
    int x = (t >= s) ? lds[t - s] : 0;
    __syncthreads();
    lds[t] += x;
    __syncthreads();
  }
  if (t < nbk) {
    boff[t] = lds[t] - v;
    gcur[t] = lds[t] - v;
  }
  if (t == 0) boff[nbk] = E;
}

__global__ __launch_bounds__(256) void partition(const int* __restrict__ src,
                                                 const int* __restrict__ dst,
                                                 int* __restrict__ gcur,
                                                 unsigned* __restrict__ part, int E, int nbk) {
  __shared__ int cnt[NBK_MAX];
  __shared__ int base[NBK_MAX];
  const int t = threadIdx.x;
  for (int j = t; j < nbk; j += 256) cnt[j] = 0;
  __syncthreads();
  const int e0 = blockIdx.x * 4096;
  unsigned mypk[16];
  int mybk[16];
#pragma unroll
  for (int u = 0; u < 16; ++u) {
    int e = e0 + u * 256 + t;
    if (e < E) {
      int d = dst[e];
      mypk[u] = (unsigned)src[e] | ((unsigned)(d & 255) << 17);
      mybk[u] = d >> 8;
      atomicAdd(&cnt[mybk[u]], 1);
    } else {
      mybk[u] = -1;
    }
  }
  __syncthreads();
  for (int j = t; j < nbk; j += 256) {
    int c = cnt[j];
    base[j] = c ? atomicAdd(&gcur[j], c) : 0;
    cnt[j] = 0;
  }
  __syncthreads();
#pragma unroll
  for (int u = 0; u < 16; ++u) {
    if (mybk[u] >= 0) {
      int r = atomicAdd(&cnt[mybk[u]], 1);
      part[base[mybk[u]] + r] = mypk[u];
    }
  }
}

__global__ __launch_bounds__(256) void bucket_csr(const unsigned* __restrict__ part,
                                                  const int* __restrict__ boff,
                                                  int* __restrict__ offs, int* __restrict__ srcs,
                                                  float* __restrict__ dinv, int N, int E) {
  __shared__ unsigned pk[8192];
  __shared__ int ssrc[8192];
  __shared__ int cnt[256];
  __shared__ int offl[256];
  __shared__ int cur[256];
  const int b = blockIdx.x;
  const int t = threadIdx.x;
  const int e0 = boff[b];
  int ne = boff[b + 1] - e0;
  if (ne > 8192) ne = 8192;
  cnt[t] = 0;
  __syncthreads();
  for (int i = t; i < ne; i += 256) {
    unsigned v = part[e0 + i];
    pk[i] = v;
    atomicAdd(&cnt[v >> 17], 1);
  }
  __syncthreads();
  int vv = cnt[t];
  offl[t] = vv;
  __syncthreads();
  for (int s = 1; s < 256; s <<= 1) {
    int x = (t >= s) ? offl[t - s] : 0;
    __syncthreads();
    offl[t] += x;
    __syncthreads();
  }
  int excl = offl[t] - vv;
  cur[t] = excl;
  __syncthreads();
  for (int i = t; i < ne; i += 256) {
    unsigned p = pk[i];
    int dl = p >> 17;
    int r = atomicAdd(&cur[dl], 1);
    ssrc[r] = (int)(p & 0x1FFFF);
  }
  __syncthreads();
  for (int i = t; i < ne; i += 256) srcs[e0 + i] = ssrc[i];
  int node = b * 256 + t;
  if (node < N) {
    offs[node] = e0 + excl;
    dinv[node] = rsqrtf((float)(vv + 1));
  }
  if (b == gridDim.x - 1 && t == 0) offs[N] = E;
}

// ================= weight prep: transpose + hi/lo bf16 split =================

__global__ void wprep(const float* __restrict__ W, unsigned short* __restrict__ hi,
                      unsigned short* __restrict__ lo, int K, int N) {
  int i = blockIdx.x * 256 + threadIdx.x;
  if (i >= K * N) return;
  int k = i / N, n = i - k * N;
  float v = W[i];
  unsigned short h = f2bf_rne(v);
  hi[(size_t)n * K + k] = h;
  lo[(size_t)n * K + k] = f2bf_rne(v - bf2f(h));
}

// ================= MFMA GEMM =================
// Out (bf16) written COLUMN-SLICED: [SLICES][M][BN/SLICES]

template <int K, int BN, int SLICES, bool BNRELU>
__global__ __launch_bounds__(256) void mfma_gemm(const float* __restrict__ A,
                                                 const unsigned short* __restrict__ Bt_hi,
                                                 const unsigned short* __restrict__ Bt_lo,
                                                 const float* __restrict__ ss,
                                                 const float* __restrict__ dinv,
                                                 unsigned short* __restrict__ Out, int M) {
  constexpr int BM = 128;
  constexpr int CS = BN / SLICES;  // = 16
  __shared__ unsigned short Ah[BM * 32];
  __shared__ unsigned short Al[BM * 32];
  __shared__ unsigned short Bh[BN * 32];
  __shared__ unsigned short Bl[BN * 32];

  const int tid = threadIdx.x;
  const int wave = tid >> 6;
  const int lane = tid & 63;
  const int lg = lane >> 4;
  const int lr = lane & 15;
  const int row0 = blockIdx.x * BM;

  f32x4 acc[2][BN / 16];
#pragma unroll
  for (int f = 0; f < 2; ++f)
#pragma unroll
    for (int j = 0; j < BN / 16; ++j) acc[f][j] = (f32x4){0.f, 0.f, 0.f, 0.f};

  for (int k0 = 0; k0 < K; k0 += 32) {
    __syncthreads();
#pragma unroll
    for (int it = 0; it < 4; ++it) {
      int m = it * 32 + (tid >> 3);
      int c2 = tid & 7;
      float4 v = {0.f, 0.f, 0.f, 0.f};
      if (row0 + m < M) v = *(const float4*)&A[(size_t)(row0 + m) * K + k0 + c2 * 4];
      if constexpr (BNRELU) {
        int kk = k0 + c2 * 4;
        float4 sc = *(const float4*)&ss[kk];
        float4 sh = *(const float4*)&ss[K + kk];
        v.x = fmaxf(0.f, fmaf(v.x, sc.x, sh.x));
        v.y = fmaxf(0.f, fmaf(v.y, sc.y, sh.y));
        v.z = fmaxf(0.f, fmaf(v.z, sc.z, sh.z));
        v.w = fmaxf(0.f, fmaf(v.w, sc.w, sh.w));
      }
      float vv[4] = {v.x, v.y, v.z, v.w};
      u16x4 h4, l4;
#pragma unroll
      for (int i = 0; i < 4; ++i) {
        unsigned short h = f2bf_rne(vv[i]);
        h4[i] = h;
        l4[i] = f2bf_rne(vv[i] - bf2f(h));
      }
      int pr = (m >> 1) & 3;
      int base = m * 32 + (((c2 >> 1) ^ pr) * 8) + (c2 & 1) * 4;
      *(u16x4*)&Ah[base] = h4;
      *(u16x4*)&Al[base] = l4;
    }
#pragma unroll
    for (int it = 0; it < BN / 64; ++it) {
      int n = it * 64 + (tid >> 2);
      int c = tid & 3;
      int pr = (n >> 1) & 3;
      int base = n * 32 + ((c ^ pr) * 8);
      *(u16x8*)&Bh[base] = *(const u16x8*)&Bt_hi[(size_t)n * K + k0 + c * 8];
      *(u16x8*)&Bl[base] = *(const u16x8*)&Bt_lo[(size_t)n * K + k0 + c * 8];
    }
    __syncthreads();

    bf16x8 afh[2], afl[2];
#pragma unroll
    for (int f = 0; f < 2; ++f) {
      int m = wave * 32 + f * 16 + lr;
      int pr = (m >> 1) & 3;
      int base = m * 32 + ((lg ^ pr) * 8);
      afh[f] = *(const bf16x8*)&Ah[base];
      afl[f] = *(const bf16x8*)&Al[base];
    }
#pragma unroll
    for (int j = 0; j < BN / 16; ++j) {
      int n = j * 16 + lr;
      int pr = (n >> 1) & 3;
      int base = n * 32 + ((lg ^ pr) * 8);
      bf16x8 bh = *(const bf16x8*)&Bh[base];
      bf16x8 bl = *(const bf16x8*)&Bl[base];
#pragma unroll
      for (int f = 0; f < 2; ++f) {
        acc[f][j] = __builtin_amdgcn_mfma_f32_16x16x32_bf16(afh[f], bh, acc[f][j], 0, 0, 0);
        acc[f][j] = __builtin_amdgcn_mfma_f32_16x16x32_bf16(afl[f], bh, acc[f][j], 0, 0, 0);
        acc[f][j] = __builtin_amdgcn_mfma_f32_16x16x32_bf16(afh[f], bl, acc[f][j], 0, 0, 0);
      }
    }
  }

  // epilogue: scale by dinv, store bf16 column-sliced [SLICES][M][CS]
#pragma unroll
  for (int f = 0; f < 2; ++f) {
#pragma unroll
    for (int r4 = 0; r4 < 4; ++r4) {
      int r = row0 + wave * 32 + f * 16 + lg * 4 + r4;
      if (r >= M) continue;
      float dv = dinv[r];
#pragma unroll
      for (int j = 0; j < BN / 16; ++j) {
        int c = j * 16 + lr;
        int slice = c / CS;
        int wi = c % CS;
        Out[((size_t)slice * M + r) * CS + wi] = f2bf_rne(acc[f][j][r4] * dv);
      }
    }
  }
}

// ================= sliced aggregation, node-per-group, 8-deep pipelined =================
// g column-sliced [NSLICE][N][CS=16] bf16. Block = (slice, 128-node chunk), 4 waves.
// Each 8-lane group owns ONE node; 8-edge predicated batches with next-batch
// srcs prefetch (~8 gathers + 8 srcs loads in flight). srcs over-allocated +32.

template <int C, int NSLICE, bool STATS, bool BIAS>
__global__ __launch_bounds__(256) void agg_slice(const unsigned short* __restrict__ g,
                                                 const int* __restrict__ offs,
                                                 const int* __restrict__ srcs,
                                                 const float* __restrict__ dinv,
                                                 const float* __restrict__ bias,
                                                 float* __restrict__ out,
                                                 float* __restrict__ stat, int N) {
  constexpr int CS = C / NSLICE;      // 16
  constexpr int LPE = CS / 2;         // 8 lanes per node-group
  constexpr int NPW = 64 / LPE;       // 8 nodes per wave per iter
  constexpr int T = 128 / (4 * NPW);  // 4 iters -> block covers 128 nodes
  const int s = blockIdx.x;           // slice
  const int w = threadIdx.x >> 6;
  const int lane = threadIdx.x & 63;
  const int gi = lane / LPE;   // node sub-index
  const int ch2 = lane % LPE;  // channel pair within slice
  const unsigned short* gs = g + (size_t)s * N * CS;
  const size_t cb = (size_t)ch2 * 2;

  float sx = 0.f, sy = 0.f, qx = 0.f, qy = 0.f;

#pragma unroll
  for (int it = 0; it < T; ++it) {
    int node = blockIdx.y * 128 + it * (4 * NPW) + w * NPW + gi;
    if (node < N) {
      unsigned u = *(const unsigned*)&gs[(size_t)node * CS + cb];
      float ax = __builtin_bit_cast(float, u << 16);
      float ay = __builtin_bit_cast(float, u & 0xffff0000u);

      const int e0 = offs[node], e1 = offs[node + 1];
      const int nb = (e1 - e0 + 7) >> 3;
      int sA[8], sB[8];
#pragma unroll
      for (int j = 0; j < 8; ++j) sA[j] = srcs[e0 + j];  // padded alloc: safe
      for (int b = 0; b < nb; ++b) {
        const int base = e0 + b * 8;
#pragma unroll
        for (int j = 0; j < 8; ++j) sB[j] = srcs[base + 8 + j];  // prefetch next
        unsigned uu[8];
#pragma unroll
        for (int j = 0; j < 8; ++j) {
          uu[j] = 0u;
          if (base + j < e1) uu[j] = *(const unsigned*)&gs[(size_t)sA[j] * CS + cb];
        }
#pragma unroll
        for (int j = 0; j < 8; ++j) {
          ax += __builtin_bit_cast(float, uu[j] << 16);
          ay += __builtin_bit_cast(float, uu[j] & 0xffff0000u);
        }
#pragma unroll
        for (int j = 0; j < 8; ++j) sA[j] = sB[j];
      }
      float dv = dinv[node];
      float ox = ax * dv, oy = ay * dv;
      if constexpr (BIAS) {
        ox += bias[s * CS + cb];
        oy += bias[s * CS + cb + 1];
      }
      *(float2*)&out[(size_t)node * C + s * CS + cb] = (float2){ox, oy};
      if constexpr (STATS) {
        sx += ox;
        sy += oy;
        qx += ox * ox;
        qy += oy * oy;
      }
    }
  }

  if constexpr (STATS) {
    __shared__ float red[256][4];
    red[threadIdx.x][0] = sx;
    red[threadIdx.x][1] = sy;
    red[threadIdx.x][2] = qx;
    red[threadIdx.x][3] = qy;
    __syncthreads();
    if (threadIdx.x < LPE) {
      float a0 = 0.f, a1 = 0.f, a2 = 0.f, a3 = 0.f;
      for (int k = threadIdx.x; k < 256; k += LPE) {
        a0 += red[k][0];
        a1 += red[k][1];
        a2 += red[k][2];
        a3 += red[k][3];
      }
      atomicAdd(&stat[s * CS + threadIdx.x * 2], a0);
      atomicAdd(&stat[s * CS + threadIdx.x * 2 + 1], a1);
      atomicAdd(&stat[C + s * CS + threadIdx.x * 2], a2);
      atomicAdd(&stat[C + s * CS + threadIdx.x * 2 + 1], a3);
    }
  }
}

// ================= BN finalize =================

template <int C>
__global__ void bn_finalize(const float* __restrict__ stat, const float* __restrict__ gamma,
                            const float* __restrict__ beta, float* __restrict__ ss, int N) {
  int c = threadIdx.x;
  if (c >= C) return;
  float mu = stat[c] / (float)N;
  float var = stat[C + c] / (float)N - mu * mu;
  float rs = rsqrtf(var + BN_EPS);
  float sc = gamma[c] * rs;
  ss[c] = sc;
  ss[C + c] = beta[c] - mu * sc;
}

// ================= launch =================

extern "C" void kernel_launch(void* const* d_in, const int* in_sizes, int n_in, void* d_out,
                              int out_size, void* d_ws, size_t ws_size, hipStream_t stream) {
  const float* x = (const float*)d_in[0];
  const int* ei = (const int*)d_in[1];
  const float* W1 = (const float*)d_in[2];
  const float* gamma1 = (const float*)d_in[4];
  const float* beta1 = (const float*)d_in[5];
  const float* W2 = (const float*)d_in[6];
  const float* gamma2 = (const float*)d_in[8];
  const float* beta2 = (const float*)d_in[9];
  const float* W3 = (const float*)d_in[10];
  const float* b3 = (const float*)d_in[11];
  float* out = (float*)d_out;

  const int N = in_sizes[0] / IN_CH;  // 100000
  const int E = in_sizes[1] / 2;      // 1600000
  const int* e_src = ei;
  const int* e_dst = ei + E;
  const int nbk = (N + 255) >> 8;  // 391

  char* ws = (char*)d_ws;
  size_t off = 0;
  auto alloc = [&](size_t bytes) {
    size_t r = off;
    off += (bytes + 1023) & ~(size_t)1023;
    return r;
  };
  int* bcnt = (int*)(ws + alloc(NBK_MAX * 4));
  int* boff = (int*)(ws + alloc((NBK_MAX + 1) * 4));
  int* gcur = (int*)(ws + alloc(NBK_MAX * 4));
  unsigned* part = (unsigned*)(ws + alloc((size_t)E * 4));
  int* offs = (int*)(ws + alloc((size_t)(N + 1) * 4));
  int* srcs = (int*)(ws + alloc(((size_t)E + 32) * 4));  // +32: speculative reads
  float* dinv = (float*)(ws + alloc((size_t)N * 4));
  unsigned short* Wt1h = (unsigned short*)(ws + alloc(256 * 128 * 2));
  unsigned short* Wt1l = (unsigned short*)(ws + alloc(256 * 128 * 2));
  unsigned short* Wt2h = (unsigned short*)(ws + alloc(128 * 64 * 2));
  unsigned short* Wt2l = (unsigned short*)(ws + alloc(128 * 64 * 2));
  unsigned short* Wt3h = (unsigned short*)(ws + alloc(64 * 64 * 2));
  unsigned short* Wt3l = (unsigned short*)(ws + alloc(64 * 64 * 2));
  float* stat1 = (float*)(ws + alloc(256 * 4));
  float* stat2 = (float*)(ws + alloc(128 * 4));
  float* ss1 = (float*)(ws + alloc(256 * 4));
  float* ss2 = (float*)(ws + alloc(128 * 4));
  unsigned short* g = (unsigned short*)(ws + alloc((size_t)N * 128 * 2));
  float* h = (float*)(ws + alloc((size_t)N * 128 * 4));

  hipMemsetAsync(bcnt, 0, NBK_MAX * 4, stream);
  hipMemsetAsync(stat1, 0, 256 * 4, stream);
  hipMemsetAsync(stat2, 0, 128 * 4, stream);

  bucket_hist<<<2048, 256, 0, stream>>>(e_dst, bcnt, E, nbk);
  bucket_scan<<<1, 512, 0, stream>>>(bcnt, boff, gcur, E, nbk);
  partition<<<(E + 4095) / 4096, 256, 0, stream>>>(e_src, e_dst, gcur, part, E, nbk);
  bucket_csr<<<nbk, 256, 0, stream>>>(part, boff, offs, srcs, dinv, N, E);

  wprep<<<(256 * 128 + 255) / 256, 256, 0, stream>>>(W1, Wt1h, Wt1l, 256, 128);
  wprep<<<(128 * 64 + 255) / 256, 256, 0, stream>>>(W2, Wt2h, Wt2l, 128, 64);
  wprep<<<(64 * 64 + 255) / 256, 256, 0, stream>>>(W3, Wt3h, Wt3l, 64, 64);

  const int gM = (N + 127) / 128;        // 782
  const int nch = (N + 127) / 128;       // node chunks
  const dim3 gAgg1(8, nch);              // layer 1: 8 slices
  const dim3 gAgg2(4, nch);              // layers 2/3: 4 slices

  // ---- layer 1: 256 -> 128 ----
  mfma_gemm<256, 128, 8, false><<<gM, 256, 0, stream>>>(x, Wt1h, Wt1l, nullptr, dinv, g, N);
  agg_slice<128, 8, true, false><<<gAgg1, 256, 0, stream>>>(g, offs, srcs, dinv, nullptr, h,
                                                            stat1, N);
  bn_finalize<128><<<1, 128, 0, stream>>>(stat1, gamma1, beta1, ss1, N);

  // ---- layer 2: 128 -> 64 (BN+ReLU fused into A staging) ----
  mfma_gemm<128, 64, 4, true><<<gM, 256, 0, stream>>>(h, Wt2h, Wt2l, ss1, dinv, g, N);
  agg_slice<64, 4, true, false><<<gAgg2, 256, 0, stream>>>(g, offs, srcs, dinv, nullptr, h,
                                                           stat2, N);
  bn_finalize<64><<<1, 64, 0, stream>>>(stat2, gamma2, beta2, ss2, N);

  // ---- layer 3: 64 -> 64 ----
  mfma_gemm<64, 64, 4, true><<<gM, 256, 0, stream>>>(h, Wt3h, Wt3l, ss2, dinv, g, N);
  agg_slice<64, 4, false, true><<<gAgg2, 256, 0, stream>>>(g, offs, srcs, dinv, b3, out, nullptr,
                                                           N);
}